// Round 7
// baseline (556.619 us; speedup 1.0000x reference)
//
#include <hip/hip_runtime.h>

#define M_DIM 16384
#define N_DIM 4096
#define K_DIM 4096
#define NCLUST 16

#define BM 256
#define BN 256
#define BKB 128               // K-tile in BYTES per row (128 fp8 elements)
#define NT (K_DIM / BKB)      // 32 K-tiles

typedef unsigned short u16;
typedef unsigned char u8;
typedef float floatx4 __attribute__((ext_vector_type(4)));
typedef int int4v __attribute__((ext_vector_type(4)));
typedef int int8v __attribute__((ext_vector_type(8)));

typedef const unsigned int __attribute__((address_space(1))) gu32;
typedef unsigned int __attribute__((address_space(3))) lu32;

// float -> OCP e4m3fn with RNE (values are pre-scaled, |x| << 448)
__device__ __forceinline__ unsigned f2fp8(float x) {
  union { float f; unsigned u; } a; a.f = x;
  unsigned s = (a.u >> 24) & 0x80u;
  float ax = fabsf(x);
  if (ax >= 448.f) return s | 0x7Eu;
  if (ax < 0.015625f) {                       // subnormal: step 2^-9
    unsigned q = (unsigned)rintf(ax * 512.0f);
    return s | q;
  }
  unsigned u = a.u & 0x7FFFFFFFu;
  u += 0xFFFFFu + ((u >> 20) & 1u);           // RNE into 3-bit mantissa
  unsigned E = u >> 23;
  return s | (((E - 120u) << 3) & 0x78u) | ((u >> 20) & 7u);
}

// ---------------- zero scratch accumulators ----------------
__global__ __launch_bounds__(256) void zero_kernel(float* __restrict__ p, int n) {
  int i = blockIdx.x * 256 + threadIdx.x;
  if (i < n) p[i] = 0.f;
}

// ---------------- z row-normalize -> fp8 (x64), plus copy z -> out1 ----------------
__global__ __launch_bounds__(256) void znorm_copy_kernel(const float* __restrict__ z,
                                                         float* __restrict__ out1,
                                                         u8* __restrict__ zn) {
  const int row = blockIdx.x;
  const int t = threadIdx.x;
  const size_t base = (size_t)row * K_DIM;
  const float4* zr = (const float4*)(z + base);
  float4 v[4];
  float ss = 0.f;
#pragma unroll
  for (int i = 0; i < 4; i++) {
    v[i] = zr[t + i * 256];
    ss += v[i].x * v[i].x + v[i].y * v[i].y + v[i].z * v[i].z + v[i].w * v[i].w;
  }
#pragma unroll
  for (int m = 1; m <= 32; m <<= 1) ss += __shfl_xor(ss, m, 64);
  __shared__ float red[4];
  if ((t & 63) == 0) red[t >> 6] = ss;
  __syncthreads();
  float tot = red[0] + red[1] + red[2] + red[3];
  float sc = 64.0f / fmaxf(sqrtf(tot), 1e-8f);   // x64 scaling folded into normalize
  float4* o1 = (float4*)(out1 + base);
  unsigned* znr = (unsigned*)(zn + base);
#pragma unroll
  for (int i = 0; i < 4; i++) {
    o1[t + i * 256] = v[i];
    unsigned pk = f2fp8(v[i].x * sc) | (f2fp8(v[i].y * sc) << 8) |
                  (f2fp8(v[i].z * sc) << 16) | (f2fp8(v[i].w * sc) << 24);
    znr[t + i * 256] = pk;
  }
}

// ---------------- D column squared-norms ----------------
__global__ __launch_bounds__(256) void colsq_kernel(const float* __restrict__ D,
                                                    float* __restrict__ colsq) {
  const int col = blockIdx.x * 256 + threadIdx.x;
  const int r0 = blockIdx.y * 128;
  float ss = 0.f;
#pragma unroll 4
  for (int r = 0; r < 128; r++) {
    float d = D[(size_t)(r0 + r) * N_DIM + col];
    ss += d * d;
  }
  atomicAdd(&colsq[col], ss);
}

// ---------------- D col-normalize + transpose -> fp8 (x64) DnT[N][K] ----------------
__global__ __launch_bounds__(256) void dnt_kernel(const float* __restrict__ D,
                                                  const float* __restrict__ colsq,
                                                  u8* __restrict__ dnt) {
  __shared__ float tile[64][65];
  const int c0 = blockIdx.x * 64, r0 = blockIdx.y * 64;
  const int t = threadIdx.x;
  const int tr = t >> 4;
  const int tc = (t & 15) * 4;
#pragma unroll
  for (int i = 0; i < 4; i++) {
    int row = i * 16 + tr;
    float4 v = *(const float4*)(D + (size_t)(r0 + row) * N_DIM + c0 + tc);
    tile[row][tc + 0] = v.x; tile[row][tc + 1] = v.y;
    tile[row][tc + 2] = v.z; tile[row][tc + 3] = v.w;
  }
  __syncthreads();
#pragma unroll
  for (int i = 0; i < 4; i++) {
    int nl = i * 16 + tr;
    float sc = 64.0f / fmaxf(sqrtf(colsq[c0 + nl]), 1e-8f);
    unsigned pk = f2fp8(tile[tc + 0][nl] * sc) | (f2fp8(tile[tc + 1][nl] * sc) << 8) |
                  (f2fp8(tile[tc + 2][nl] * sc) << 16) | (f2fp8(tile[tc + 3][nl] * sc) << 24);
    *(unsigned*)(dnt + (size_t)(c0 + nl) * K_DIM + r0 + tc) = pk;
  }
}

// ---------------- GEMM: 256x256, fp8 e4m3, mfma_scale 16x16x128 (unit scales) ----
// R7 = R5 schedule with register-pressure surgery to kill the 216 MB scratch
// spill: 2 staging base pointers (advanced per iter) instead of 8, uniform LDS
// dest scalars via readfirstlane, and split af reads (af01 pre-barrier, af23
// between MFMA half-groups).
__global__ __launch_bounds__(512, 1) void gemm_kernel(const u8* __restrict__ zn,
                                                      const u8* __restrict__ dnt,
                                                      float* __restrict__ s_accum) {
  __shared__ u8 ldsA[2][BM * BKB];   // 2 x 32 KB
  __shared__ u8 ldsB[2][BN * BKB];   // 2 x 32 KB -> 128 KB

  const int t = threadIdx.x;
  const int w = t >> 6, l = t & 63;
  const int lr = l & 15, lk = l >> 4;

  const int bid = blockIdx.x;
  const int swz = (bid & 7) * 128 + (bid >> 3);
  const int bx = swz & 15, by = swz >> 4;
  const int bm = by * BM, bn = bx * BN;
  const int wm = (w >> 2) * 128, wn = (w & 3) * 64;

  // ---- staging: per-lane bases (advanced by BKB per K-tile) + const offsets ----
  const int tr8 = t >> 3, ts = t & 7;
  const int ssrc = ts ^ (tr8 & 7);
  const u8* pAk = zn + (size_t)(bm + tr8) * K_DIM + ssrc * 16;
  const u8* pBk = dnt + (size_t)(bn + (t >> 8) * 64 + (tr8 & 31)) * K_DIM + ssrc * 16;
  const int aD0 = w * 1024;                         // wave-uniform LDS dest bases
  const int bD0 = ((w >> 2) * 64 + (w & 3) * 8) * BKB;

#define RFL(x) __builtin_amdgcn_readfirstlane(x)
#define STAGE_AH(BUF, MH, DK) do { \
    __builtin_amdgcn_global_load_lds((gu32*)(pAk + (size_t)((MH) * 64) * K_DIM + (DK) * BKB), \
        (lu32*)&ldsA[BUF][RFL(aD0 + (MH) * 64 * BKB)], 16, 0, 0); \
    __builtin_amdgcn_global_load_lds((gu32*)(pAk + (size_t)((MH) * 64 + 128) * K_DIM + (DK) * BKB), \
        (lu32*)&ldsA[BUF][RFL(aD0 + ((MH) * 64 + 128) * BKB)], 16, 0, 0); \
  } while (0)
#define STAGE_BH(BUF, NH, DK) do { \
    __builtin_amdgcn_global_load_lds((gu32*)(pBk + (size_t)((NH) * 32) * K_DIM + (DK) * BKB), \
        (lu32*)&ldsB[BUF][RFL(bD0 + (NH) * 32 * BKB)], 16, 0, 0); \
    __builtin_amdgcn_global_load_lds((gu32*)(pBk + (size_t)((NH) * 32 + 128) * K_DIM + (DK) * BKB), \
        (lu32*)&ldsB[BUF][RFL(bD0 + ((NH) * 32 + 128) * BKB)], 16, 0, 0); \
  } while (0)

  // ---- ds_read fragment byte offsets (3-bit row swizzle; slot0 = 2*lk) ----
  int aOff[8], bOff[4];
#pragma unroll
  for (int m = 0; m < 8; m++) {
    int row = wm + (m >> 2) * 64 + (m & 3) * 16 + lr;
    aOff[m] = row * BKB + (((lk << 1) ^ (row & 7)) * 16);
  }
#pragma unroll
  for (int n = 0; n < 4; n++) {
    int row = wn + (n >> 1) * 32 + (n & 1) * 16 + lr;
    bOff[n] = row * BKB + (((lk << 1) ^ (row & 7)) * 16);
  }

  int8v af[4], bf[2];
  floatx4 acc[8][4] = {};

#define LDFRAG(dst, base, off) do { \
    int4v _lo = *(const int4v*)((base) + (off)); \
    int4v _hi = *(const int4v*)((base) + ((off) ^ 16)); \
    dst = __builtin_shufflevector(_lo, _hi, 0, 1, 2, 3, 4, 5, 6, 7); \
  } while (0)

#define PHASE(AB, BB, MH, NH, RDA, RDB, STAGE_STMT, WAIT_STMT) do { \
    if (RDB) { \
      _Pragma("unroll") \
      for (int ni = 0; ni < 2; ni++) LDFRAG(bf[ni], (BB), bOff[(NH) * 2 + ni]); \
    } \
    if (RDA) { \
      _Pragma("unroll") \
      for (int mi = 0; mi < 2; mi++) LDFRAG(af[mi], (AB), aOff[(MH) * 4 + mi]); \
    } \
    STAGE_STMT; \
    WAIT_STMT; \
    __builtin_amdgcn_s_barrier(); \
    __builtin_amdgcn_s_setprio(1); \
    _Pragma("unroll") \
    for (int mi = 0; mi < 2; mi++) \
      _Pragma("unroll") \
      for (int ni = 0; ni < 2; ni++) \
        acc[(MH) * 4 + mi][(NH) * 2 + ni] = __builtin_amdgcn_mfma_scale_f32_16x16x128_f8f6f4( \
            af[mi], bf[ni], acc[(MH) * 4 + mi][(NH) * 2 + ni], 0, 0, 0, 127u, 0, 127u); \
    if (RDA) { \
      _Pragma("unroll") \
      for (int mi = 2; mi < 4; mi++) LDFRAG(af[mi], (AB), aOff[(MH) * 4 + mi]); \
    } \
    _Pragma("unroll") \
    for (int mi = 2; mi < 4; mi++) \
      _Pragma("unroll") \
      for (int ni = 0; ni < 2; ni++) \
        acc[(MH) * 4 + mi][(NH) * 2 + ni] = __builtin_amdgcn_mfma_scale_f32_16x16x128_f8f6f4( \
            af[mi], bf[ni], acc[(MH) * 4 + mi][(NH) * 2 + ni], 0, 0, 0, 127u, 0, 127u); \
    __builtin_amdgcn_s_setprio(0); \
    __builtin_amdgcn_s_barrier(); \
  } while (0)

  // prologue: tile0 fully + Ah0(1), Bh1(1); drain tile0, keep 2 halves in flight
  STAGE_AH(0, 0, 0); STAGE_AH(0, 1, 0); STAGE_BH(0, 0, 0); STAGE_BH(0, 1, 0);
  STAGE_AH(1, 0, 1); STAGE_BH(1, 1, 1);
  asm volatile("s_waitcnt vmcnt(4)" ::: "memory");
  __builtin_amdgcn_s_barrier();

  for (int kt = 0; kt < NT - 2; ++kt) {
    const int cb = kt & 1, nb = cb ^ 1;
    const u8* Ac = ldsA[cb]; const u8* Bc = ldsB[cb];
    PHASE(Ac, Bc, 0, 0, 1, 1, STAGE_AH(nb, 1, 1), ((void)0));
    PHASE(Ac, Bc, 0, 1, 0, 1, STAGE_BH(nb, 0, 1), ((void)0));
    PHASE(Ac, Bc, 1, 1, 1, 0, STAGE_AH(cb, 0, 2), ((void)0));
    PHASE(Ac, Bc, 1, 0, 0, 1, STAGE_BH(cb, 1, 2),
          asm volatile("s_waitcnt vmcnt(4)" ::: "memory"));
    pAk += BKB; pBk += BKB;
  }
  { // kt = NT-2: stage only tile NT-1's remaining halves; full drain at ph4
    const int cb = (NT - 2) & 1, nb = cb ^ 1;
    const u8* Ac = ldsA[cb]; const u8* Bc = ldsB[cb];
    PHASE(Ac, Bc, 0, 0, 1, 1, STAGE_AH(nb, 1, 1), ((void)0));
    PHASE(Ac, Bc, 0, 1, 0, 1, STAGE_BH(nb, 0, 1), ((void)0));
    PHASE(Ac, Bc, 1, 1, 1, 0, ((void)0), ((void)0));
    PHASE(Ac, Bc, 1, 0, 0, 1, ((void)0),
          asm volatile("s_waitcnt vmcnt(0)" ::: "memory"));
  }
  { // kt = NT-1: compute only
    const int cb = (NT - 1) & 1;
    const u8* Ac = ldsA[cb]; const u8* Bc = ldsB[cb];
    PHASE(Ac, Bc, 0, 0, 1, 1, ((void)0), ((void)0));
    PHASE(Ac, Bc, 0, 1, 0, 1, ((void)0), ((void)0));
    PHASE(Ac, Bc, 1, 1, 1, 0, ((void)0), ((void)0));
    PHASE(Ac, Bc, 1, 0, 0, 1, ((void)0), ((void)0));
  }

#undef PHASE
#undef LDFRAG
#undef STAGE_AH
#undef STAGE_BH
#undef RFL

  // ---- epilogue: per-row sum of squares over this wave's 64 columns ----
  __syncthreads();
  float* red = (float*)&ldsA[0][0];    // [256 rows][4 wave-cols]
#pragma unroll
  for (int m = 0; m < 8; m++) {
#pragma unroll
    for (int r = 0; r < 4; r++) {
      float v = 0.f;
#pragma unroll
      for (int n = 0; n < 4; n++) { float x = acc[m][n][r]; v += x * x; }
      v += __shfl_xor(v, 1, 64);
      v += __shfl_xor(v, 2, 64);
      v += __shfl_xor(v, 4, 64);
      v += __shfl_xor(v, 8, 64);
      if (lr == 0) {
        int lrow = wm + (m >> 2) * 64 + (m & 3) * 16 + lk * 4 + r;
        red[lrow * 4 + (w & 3)] = v;
      }
    }
  }
  __syncthreads();
  if (t < 256) {
    float s = red[t * 4 + 0] + red[t * 4 + 1] + red[t * 4 + 2] + red[t * 4 + 3];
    s_accum[(size_t)(bm + t) * NCLUST + bx] = s;
  }
}

// ---------------- softmax over 16 clusters per row ----------------
__global__ __launch_bounds__(256) void softmax_kernel(const float* __restrict__ s_accum,
                                                      float* __restrict__ out0) {
  int r = blockIdx.x * 256 + threadIdx.x;
  const float4* sp = (const float4*)(s_accum + (size_t)r * 16);
  float v[16];
#pragma unroll
  for (int i = 0; i < 4; i++) {
    float4 a = sp[i];
    v[i * 4 + 0] = a.x; v[i * 4 + 1] = a.y; v[i * 4 + 2] = a.z; v[i * 4 + 3] = a.w;
  }
  // logits = (s_scaled / 2^24) / TEMP ; eta*d cancels in softmax
  const float lsc = 5.9604644775390625e-7f;   // 10 / 2^24
  float mx = -1e30f;
#pragma unroll
  for (int i = 0; i < 16; i++) { v[i] *= lsc; mx = fmaxf(mx, v[i]); }
  float sum = 0.f;
#pragma unroll
  for (int i = 0; i < 16; i++) { v[i] = __expf(v[i] - mx); sum += v[i]; }
  float rs = 1.0f / sum;
  float4* op = (float4*)(out0 + (size_t)r * 16);
#pragma unroll
  for (int i = 0; i < 4; i++) {
    float4 a;
    a.x = v[i * 4 + 0] * rs; a.y = v[i * 4 + 1] * rs;
    a.z = v[i * 4 + 2] * rs; a.w = v[i * 4 + 3] * rs;
    op[i] = a;
  }
}

extern "C" void kernel_launch(void* const* d_in, const int* in_sizes, int n_in,
                              void* d_out, int out_size, void* d_ws, size_t ws_size,
                              hipStream_t stream) {
  const float* z = (const float*)d_in[0];
  const float* D = (const float*)d_in[1];
  float* out0 = (float*)d_out;
  float* out1 = out0 + (size_t)M_DIM * NCLUST;

  char* ws = (char*)d_ws;
  u8* zn   = (u8*)ws;                                                 // 64 MB
  u8* dnt  = (u8*)(ws + (size_t)M_DIM * K_DIM);                       // 16 MB
  float* colsq   = (float*)(ws + (size_t)M_DIM * K_DIM + (size_t)N_DIM * K_DIM);
  float* s_accum = colsq + N_DIM;

  zero_kernel<<<(N_DIM + 255) / 256, 256, 0, stream>>>(colsq, N_DIM);
  znorm_copy_kernel<<<M_DIM, 256, 0, stream>>>(z, out1, zn);
  colsq_kernel<<<dim3(N_DIM / 256, N_DIM / 128), 256, 0, stream>>>(D, colsq);
  dnt_kernel<<<dim3(N_DIM / 64, N_DIM / 64), 256, 0, stream>>>(D, colsq, dnt);
  gemm_kernel<<<(M_DIM / BM) * (N_DIM / BN), 512, 0, stream>>>(zn, dnt, s_accum);
  softmax_kernel<<<M_DIM / 256, 256, 0, stream>>>(s_accum, out0);
}

// Round 8
// 473.210 us; speedup vs baseline: 1.1763x; 1.1763x over previous
//
#include <hip/hip_runtime.h>

#define M_DIM 16384
#define N_DIM 4096
#define K_DIM 4096
#define NCLUST 16

#define BM 256
#define BN 256
#define BKB 128               // K-tile in BYTES per row (128 fp8 elements)
#define NT (K_DIM / BKB)      // 32 K-tiles

typedef unsigned short u16;
typedef unsigned char u8;
typedef float floatx4 __attribute__((ext_vector_type(4)));
typedef int int4v __attribute__((ext_vector_type(4)));
typedef int int8v __attribute__((ext_vector_type(8)));

typedef const unsigned int __attribute__((address_space(1))) gu32;
typedef unsigned int __attribute__((address_space(3))) lu32;

// float -> OCP e4m3fn with RNE (values are pre-scaled, |x| << 448)
__device__ __forceinline__ unsigned f2fp8(float x) {
  union { float f; unsigned u; } a; a.f = x;
  unsigned s = (a.u >> 24) & 0x80u;
  float ax = fabsf(x);
  if (ax >= 448.f) return s | 0x7Eu;
  if (ax < 0.015625f) {                       // subnormal: step 2^-9
    unsigned q = (unsigned)rintf(ax * 512.0f);
    return s | q;
  }
  unsigned u = a.u & 0x7FFFFFFFu;
  u += 0xFFFFFu + ((u >> 20) & 1u);           // RNE into 3-bit mantissa
  unsigned E = u >> 23;
  return s | (((E - 120u) << 3) & 0x78u) | ((u >> 20) & 7u);
}

// ---------------- zero scratch accumulators ----------------
__global__ __launch_bounds__(256) void zero_kernel(float* __restrict__ p, int n) {
  int i = blockIdx.x * 256 + threadIdx.x;
  if (i < n) p[i] = 0.f;
}

// ---------------- z row-normalize -> fp8 (x64), plus copy z -> out1 ----------------
__global__ __launch_bounds__(256) void znorm_copy_kernel(const float* __restrict__ z,
                                                         float* __restrict__ out1,
                                                         u8* __restrict__ zn) {
  const int row = blockIdx.x;
  const int t = threadIdx.x;
  const size_t base = (size_t)row * K_DIM;
  const float4* zr = (const float4*)(z + base);
  float4 v[4];
  float ss = 0.f;
#pragma unroll
  for (int i = 0; i < 4; i++) {
    v[i] = zr[t + i * 256];
    ss += v[i].x * v[i].x + v[i].y * v[i].y + v[i].z * v[i].z + v[i].w * v[i].w;
  }
#pragma unroll
  for (int m = 1; m <= 32; m <<= 1) ss += __shfl_xor(ss, m, 64);
  __shared__ float red[4];
  if ((t & 63) == 0) red[t >> 6] = ss;
  __syncthreads();
  float tot = red[0] + red[1] + red[2] + red[3];
  float sc = 64.0f / fmaxf(sqrtf(tot), 1e-8f);   // x64 scaling folded into normalize
  float4* o1 = (float4*)(out1 + base);
  unsigned* znr = (unsigned*)(zn + base);
#pragma unroll
  for (int i = 0; i < 4; i++) {
    o1[t + i * 256] = v[i];
    unsigned pk = f2fp8(v[i].x * sc) | (f2fp8(v[i].y * sc) << 8) |
                  (f2fp8(v[i].z * sc) << 16) | (f2fp8(v[i].w * sc) << 24);
    znr[t + i * 256] = pk;
  }
}

// ---------------- D column squared-norms ----------------
__global__ __launch_bounds__(256) void colsq_kernel(const float* __restrict__ D,
                                                    float* __restrict__ colsq) {
  const int col = blockIdx.x * 256 + threadIdx.x;
  const int r0 = blockIdx.y * 128;
  float ss = 0.f;
#pragma unroll 4
  for (int r = 0; r < 128; r++) {
    float d = D[(size_t)(r0 + r) * N_DIM + col];
    ss += d * d;
  }
  atomicAdd(&colsq[col], ss);
}

// ---------------- D col-normalize + transpose -> fp8 (x64) DnT[N][K] ----------------
__global__ __launch_bounds__(256) void dnt_kernel(const float* __restrict__ D,
                                                  const float* __restrict__ colsq,
                                                  u8* __restrict__ dnt) {
  __shared__ float tile[64][65];
  const int c0 = blockIdx.x * 64, r0 = blockIdx.y * 64;
  const int t = threadIdx.x;
  const int tr = t >> 4;
  const int tc = (t & 15) * 4;
#pragma unroll
  for (int i = 0; i < 4; i++) {
    int row = i * 16 + tr;
    float4 v = *(const float4*)(D + (size_t)(r0 + row) * N_DIM + c0 + tc);
    tile[row][tc + 0] = v.x; tile[row][tc + 1] = v.y;
    tile[row][tc + 2] = v.z; tile[row][tc + 3] = v.w;
  }
  __syncthreads();
#pragma unroll
  for (int i = 0; i < 4; i++) {
    int nl = i * 16 + tr;
    float sc = 64.0f / fmaxf(sqrtf(colsq[c0 + nl]), 1e-8f);
    unsigned pk = f2fp8(tile[tc + 0][nl] * sc) | (f2fp8(tile[tc + 1][nl] * sc) << 8) |
                  (f2fp8(tile[tc + 2][nl] * sc) << 16) | (f2fp8(tile[tc + 3][nl] * sc) << 24);
    *(unsigned*)(dnt + (size_t)(c0 + nl) * K_DIM + r0 + tc) = pk;
  }
}

// ---------------- GEMM: 256x256, fp8 e4m3, mfma_scale 16x16x128 (unit scales) ----
// R8 = R5 schedule verbatim; ONLY change: fragments are assembled by writing
// the two ds_read_b128 results directly into the int8v halves (pointer-cast),
// not via __builtin_shufflevector — kills the lo/hi temporary copies that
// pushed arch-VGPR past the 128 cap (256 unified - 128 AGPR acc) and caused
// the 216 MB scratch spill seen in R5-R7.
__global__ __launch_bounds__(512, 1) void gemm_kernel(const u8* __restrict__ zn,
                                                      const u8* __restrict__ dnt,
                                                      float* __restrict__ s_accum) {
  __shared__ u8 ldsA[2][BM * BKB];   // 2 x 32 KB
  __shared__ u8 ldsB[2][BN * BKB];   // 2 x 32 KB -> 128 KB

  const int t = threadIdx.x;
  const int w = t >> 6, l = t & 63;
  const int lr = l & 15, lk = l >> 4;

  const int bid = blockIdx.x;
  const int swz = (bid & 7) * 128 + (bid >> 3);
  const int bx = swz & 15, by = swz >> 4;
  const int bm = by * BM, bn = bx * BN;
  const int wm = (w >> 2) * 128, wn = (w & 3) * 64;

  // ---- staging source pointers (pre-swizzled), LDS wave-uniform dests (bytes) ----
  const int tr8 = t >> 3, ts = t & 7;
  const int ssrc = ts ^ (tr8 & 7);
  const u8* pA[2][2]; const u8* pB[2][2];
  int aDst[2][2], bDst[2][2];
#pragma unroll
  for (int mh = 0; mh < 2; mh++)
#pragma unroll
    for (int r = 0; r < 2; r++) {
      int row = mh * 64 + r * 128 + tr8;
      pA[mh][r] = zn + (size_t)(bm + row) * K_DIM + ssrc * 16;
      aDst[mh][r] = (mh * 64 + r * 128) * BKB + w * 1024;
    }
#pragma unroll
  for (int nh = 0; nh < 2; nh++)
#pragma unroll
    for (int r = 0; r < 2; r++) {
      int row = nh * 32 + (2 * r + (t >> 8)) * 64 + (tr8 & 31);
      pB[nh][r] = dnt + (size_t)(bn + row) * K_DIM + ssrc * 16;
      bDst[nh][r] = (nh * 32 + (2 * r + (w >> 2)) * 64 + (w & 3) * 8) * BKB;
    }

#define STAGE_AH(BUF, MH, KT) do { \
    __builtin_amdgcn_global_load_lds((gu32*)(pA[MH][0] + (KT) * BKB), (lu32*)&ldsA[BUF][aDst[MH][0]], 16, 0, 0); \
    __builtin_amdgcn_global_load_lds((gu32*)(pA[MH][1] + (KT) * BKB), (lu32*)&ldsA[BUF][aDst[MH][1]], 16, 0, 0); \
  } while (0)
#define STAGE_BH(BUF, NH, KT) do { \
    __builtin_amdgcn_global_load_lds((gu32*)(pB[NH][0] + (KT) * BKB), (lu32*)&ldsB[BUF][bDst[NH][0]], 16, 0, 0); \
    __builtin_amdgcn_global_load_lds((gu32*)(pB[NH][1] + (KT) * BKB), (lu32*)&ldsB[BUF][bDst[NH][1]], 16, 0, 0); \
  } while (0)

  // ---- ds_read fragment byte offsets (3-bit row swizzle; slot0 = 2*lk) ----
  int aOff[8], bOff[4];
#pragma unroll
  for (int m = 0; m < 8; m++) {
    int row = wm + (m >> 2) * 64 + (m & 3) * 16 + lr;
    aOff[m] = row * BKB + (((lk << 1) ^ (row & 7)) * 16);
  }
#pragma unroll
  for (int n = 0; n < 4; n++) {
    int row = wn + (n >> 1) * 32 + (n & 1) * 16 + lr;
    bOff[n] = row * BKB + (((lk << 1) ^ (row & 7)) * 16);
  }

  int8v af[4], bf[2];
  floatx4 acc[8][4] = {};

  // Direct half-writes into the 8-wide fragment (no shufflevector temps).
#define LDFRAG(F, base, off) do { \
    int4v* _h = (int4v*)&(F); \
    _h[0] = *(const int4v*)((base) + (off)); \
    _h[1] = *(const int4v*)((base) + ((off) ^ 16)); \
  } while (0)

#define PHASE(AB, BB, MH, NH, RDA, RDB, STAGE_STMT, WAIT_STMT) do { \
    if (RDA) { \
      _Pragma("unroll") \
      for (int mi = 0; mi < 4; mi++) LDFRAG(af[mi], (AB), aOff[(MH) * 4 + mi]); \
    } \
    if (RDB) { \
      _Pragma("unroll") \
      for (int ni = 0; ni < 2; ni++) LDFRAG(bf[ni], (BB), bOff[(NH) * 2 + ni]); \
    } \
    STAGE_STMT; \
    WAIT_STMT; \
    __builtin_amdgcn_s_barrier(); \
    asm volatile("s_waitcnt lgkmcnt(0)" ::: "memory"); \
    __builtin_amdgcn_s_setprio(1); \
    _Pragma("unroll") \
    for (int mi = 0; mi < 4; mi++) \
      _Pragma("unroll") \
      for (int ni = 0; ni < 2; ni++) \
        acc[(MH) * 4 + mi][(NH) * 2 + ni] = __builtin_amdgcn_mfma_scale_f32_16x16x128_f8f6f4( \
            af[mi], bf[ni], acc[(MH) * 4 + mi][(NH) * 2 + ni], 0, 0, 0, 127u, 0, 127u); \
    __builtin_amdgcn_s_setprio(0); \
    __builtin_amdgcn_s_barrier(); \
  } while (0)

  // prologue: tile0 fully + Ah0(1), Bh1(1); drain tile0, keep 2 halves in flight
  STAGE_AH(0, 0, 0); STAGE_AH(0, 1, 0); STAGE_BH(0, 0, 0); STAGE_BH(0, 1, 0);
  STAGE_AH(1, 0, 1); STAGE_BH(1, 1, 1);
  asm volatile("s_waitcnt vmcnt(4)" ::: "memory");
  __builtin_amdgcn_s_barrier();

  for (int kt = 0; kt < NT - 2; ++kt) {
    const int cb = kt & 1, nb = cb ^ 1;
    const u8* Ac = ldsA[cb]; const u8* Bc = ldsB[cb];
    PHASE(Ac, Bc, 0, 0, 1, 1, STAGE_AH(nb, 1, kt + 1), ((void)0));
    PHASE(Ac, Bc, 0, 1, 0, 1, STAGE_BH(nb, 0, kt + 1), ((void)0));
    PHASE(Ac, Bc, 1, 1, 1, 0, STAGE_AH(cb, 0, kt + 2), ((void)0));
    PHASE(Ac, Bc, 1, 0, 0, 1, STAGE_BH(cb, 1, kt + 2),
          asm volatile("s_waitcnt vmcnt(4)" ::: "memory"));
  }
  { // kt = NT-2: stage only tile NT-1's remaining halves; full drain at ph4
    const int cb = (NT - 2) & 1, nb = cb ^ 1;
    const u8* Ac = ldsA[cb]; const u8* Bc = ldsB[cb];
    PHASE(Ac, Bc, 0, 0, 1, 1, STAGE_AH(nb, 1, NT - 1), ((void)0));
    PHASE(Ac, Bc, 0, 1, 0, 1, STAGE_BH(nb, 0, NT - 1), ((void)0));
    PHASE(Ac, Bc, 1, 1, 1, 0, ((void)0), ((void)0));
    PHASE(Ac, Bc, 1, 0, 0, 1, ((void)0),
          asm volatile("s_waitcnt vmcnt(0)" ::: "memory"));
  }
  { // kt = NT-1: compute only
    const int cb = (NT - 1) & 1;
    const u8* Ac = ldsA[cb]; const u8* Bc = ldsB[cb];
    PHASE(Ac, Bc, 0, 0, 1, 1, ((void)0), ((void)0));
    PHASE(Ac, Bc, 0, 1, 0, 1, ((void)0), ((void)0));
    PHASE(Ac, Bc, 1, 1, 1, 0, ((void)0), ((void)0));
    PHASE(Ac, Bc, 1, 0, 0, 1, ((void)0), ((void)0));
  }

#undef PHASE
#undef LDFRAG
#undef STAGE_AH
#undef STAGE_BH

  // ---- epilogue: per-row sum of squares over this wave's 64 columns ----
  __syncthreads();
  float* red = (float*)&ldsA[0][0];    // [256 rows][4 wave-cols]
#pragma unroll
  for (int m = 0; m < 8; m++) {
#pragma unroll
    for (int r = 0; r < 4; r++) {
      float v = 0.f;
#pragma unroll
      for (int n = 0; n < 4; n++) { float x = acc[m][n][r]; v += x * x; }
      v += __shfl_xor(v, 1, 64);
      v += __shfl_xor(v, 2, 64);
      v += __shfl_xor(v, 4, 64);
      v += __shfl_xor(v, 8, 64);
      if (lr == 0) {
        int lrow = wm + (m >> 2) * 64 + (m & 3) * 16 + lk * 4 + r;
        red[lrow * 4 + (w & 3)] = v;
      }
    }
  }
  __syncthreads();
  if (t < 256) {
    float s = red[t * 4 + 0] + red[t * 4 + 1] + red[t * 4 + 2] + red[t * 4 + 3];
    s_accum[(size_t)(bm + t) * NCLUST + bx] = s;
  }
}

// ---------------- softmax over 16 clusters per row ----------------
__global__ __launch_bounds__(256) void softmax_kernel(const float* __restrict__ s_accum,
                                                      float* __restrict__ out0) {
  int r = blockIdx.x * 256 + threadIdx.x;
  const float4* sp = (const float4*)(s_accum + (size_t)r * 16);
  float v[16];
#pragma unroll
  for (int i = 0; i < 4; i++) {
    float4 a = sp[i];
    v[i * 4 + 0] = a.x; v[i * 4 + 1] = a.y; v[i * 4 + 2] = a.z; v[i * 4 + 3] = a.w;
  }
  // logits = (s_scaled / 2^24) / TEMP ; eta*d cancels in softmax
  const float lsc = 5.9604644775390625e-7f;   // 10 / 2^24
  float mx = -1e30f;
#pragma unroll
  for (int i = 0; i < 16; i++) { v[i] *= lsc; mx = fmaxf(mx, v[i]); }
  float sum = 0.f;
#pragma unroll
  for (int i = 0; i < 16; i++) { v[i] = __expf(v[i] - mx); sum += v[i]; }
  float rs = 1.0f / sum;
  float4* op = (float4*)(out0 + (size_t)r * 16);
#pragma unroll
  for (int i = 0; i < 4; i++) {
    float4 a;
    a.x = v[i * 4 + 0] * rs; a.y = v[i * 4 + 1] * rs;
    a.z = v[i * 4 + 2] * rs; a.w = v[i * 4 + 3] * rs;
    op[i] = a;
  }
}

extern "C" void kernel_launch(void* const* d_in, const int* in_sizes, int n_in,
                              void* d_out, int out_size, void* d_ws, size_t ws_size,
                              hipStream_t stream) {
  const float* z = (const float*)d_in[0];
  const float* D = (const float*)d_in[1];
  float* out0 = (float*)d_out;
  float* out1 = out0 + (size_t)M_DIM * NCLUST;

  char* ws = (char*)d_ws;
  u8* zn   = (u8*)ws;                                                 // 64 MB
  u8* dnt  = (u8*)(ws + (size_t)M_DIM * K_DIM);                       // 16 MB
  float* colsq   = (float*)(ws + (size_t)M_DIM * K_DIM + (size_t)N_DIM * K_DIM);
  float* s_accum = colsq + N_DIM;

  zero_kernel<<<(N_DIM + 255) / 256, 256, 0, stream>>>(colsq, N_DIM);
  znorm_copy_kernel<<<M_DIM, 256, 0, stream>>>(z, out1, zn);
  colsq_kernel<<<dim3(N_DIM / 256, N_DIM / 128), 256, 0, stream>>>(D, colsq);
  dnt_kernel<<<dim3(N_DIM / 64, N_DIM / 64), 256, 0, stream>>>(D, colsq, dnt);
  gemm_kernel<<<(M_DIM / BM) * (N_DIM / BN), 512, 0, stream>>>(zn, dnt, s_accum);
  softmax_kernel<<<M_DIM / 256, 256, 0, stream>>>(s_accum, out0);
}